// Round 11
// baseline (418.695 us; speedup 1.0000x reference)
//
#include <hip/hip_runtime.h>

#define DEVI __device__ __forceinline__

typedef __attribute__((ext_vector_type(4))) float f32x4;
typedef __attribute__((ext_vector_type(8))) short bf16x8;

static constexpr int NT = 2048;   // tokens
static constexpr int CD = 2048;   // model dim
static constexpr int NE = 8;      // experts
static constexpr int ID = 1408;   // expert ffn dim
static constexpr int SD = 2816;   // shared ffn dim
static constexpr int ROWS = 2 * NT;
static constexpr int ROWS_PAD = ROWS + 256;

DEVI unsigned short f2bf(float f) {
  unsigned u = __builtin_bit_cast(unsigned, f);
  u += 0x7fff + ((u >> 16) & 1);           // RNE
  return (unsigned short)(u >> 16);
}
DEVI float bf2f(unsigned short s) { return __builtin_bit_cast(float, (unsigned)s << 16); }
DEVI float silu_f(float z) { return z / (1.f + __expf(-z)); }

DEVI void gll16(const void* g, void* l) {
  __builtin_amdgcn_global_load_lds((__attribute__((address_space(1))) void*)(void*)g,
                                   (__attribute__((address_space(3))) void*)l, 16, 0, 0);
}

DEVI void bar_sched() {
  __builtin_amdgcn_s_barrier();
  __builtin_amdgcn_sched_barrier(0);
}
DEVI void sched0() { __builtin_amdgcn_sched_barrier(0); }
DEVI void wait_vm8() { asm volatile("s_waitcnt vmcnt(8)" ::: "memory"); }
DEVI void wait_vm4() { asm volatile("s_waitcnt vmcnt(4)" ::: "memory"); }
DEVI void wait_vm0() { asm volatile("s_waitcnt vmcnt(0)" ::: "memory"); }
DEVI void wait_lgk0() { asm volatile("s_waitcnt lgkmcnt(0)" ::: "memory"); }

// bijective XCD-chunk swizzle, CH=8 (512-thr kernels)
DEVI int swz8(int bid, int nwg) {
  constexpr int CH = 8, G = 64;
  int nfull = nwg - (nwg % G);
  if (bid >= nfull) return bid;
  int c = bid / G, r = bid % G;
  return c * G + (r % 8) * CH + (r / 8);
}
// bijective XCD-chunk swizzle, CH=16 (256-thr GEMMs)
DEVI int swz_chunk(int bid, int nwg) {
  constexpr int CH = 16, G = 8 * CH;
  int nfull = nwg - (nwg % G);
  if (bid >= nfull) return bid;
  int c = bid / G, r = bid % G;
  return c * G + (r % 8) * CH + (r / 8);
}

// ---------------- fused fp32 -> bf16 convert (7 tensors, one dispatch) -----
struct Cvt7 {
  const float* s[7];
  unsigned short* d[7];
  long long beg[8];   // prefix sums, units of 8-element groups
};
__global__ __launch_bounds__(256) void k_cvt7(Cvt7 c)
{
  const long long total = c.beg[7];
  const long long stride = (long long)gridDim.x * 256;
  for (long long i = (long long)blockIdx.x * 256 + threadIdx.x; i < total; i += stride) {
    int sg = 0;
#pragma unroll
    for (int k = 1; k < 7; ++k) if (i >= c.beg[k]) sg = k;
    long long j = i - c.beg[sg];
    float4 a = ((const float4*)c.s[sg])[2 * j];
    float4 b = ((const float4*)c.s[sg])[2 * j + 1];
    ushort4 p0 = make_ushort4(f2bf(a.x), f2bf(a.y), f2bf(a.z), f2bf(a.w));
    ushort4 p1 = make_ushort4(f2bf(b.x), f2bf(b.y), f2bf(b.z), f2bf(b.w));
    ((ushort4*)c.d[sg])[2 * j]     = p0;
    ((ushort4*)c.d[sg])[2 * j + 1] = p1;
  }
}

// ---------------- router ---------------------------------------------------
__global__ __launch_bounds__(64) void k_router(const float* __restrict__ x,
    const float* __restrict__ gw, int* __restrict__ counts,
    int* __restrict__ eidx, int* __restrict__ posn, float* __restrict__ probs)
{
  const int n = blockIdx.x;
  const int lane = threadIdx.x;
  const float4* xr = (const float4*)(x + (size_t)n * CD);
  float acc[NE];
#pragma unroll
  for (int e = 0; e < NE; ++e) acc[e] = 0.f;
  for (int i = lane; i < CD / 4; i += 64) {
    float4 xv = xr[i];
#pragma unroll
    for (int e = 0; e < NE; ++e) {
      float4 gv = ((const float4*)(gw + (size_t)e * CD))[i];
      acc[e] += xv.x * gv.x + xv.y * gv.y + xv.z * gv.z + xv.w * gv.w;
    }
  }
#pragma unroll
  for (int e = 0; e < NE; ++e) {
    float v = acc[e];
#pragma unroll
    for (int off = 32; off > 0; off >>= 1) v += __shfl_down(v, off);
    acc[e] = v;
  }
  if (lane == 0) {
    int b0 = 0; float m0 = acc[0];
#pragma unroll
    for (int e = 1; e < NE; ++e) if (acc[e] > m0) { m0 = acc[e]; b0 = e; }
    int b1 = -1; float m1 = 0.f;
#pragma unroll
    for (int e = 0; e < NE; ++e) {
      if (e == b0) continue;
      if (b1 < 0 || acc[e] > m1) { m1 = acc[e]; b1 = e; }
    }
    float d = __expf(m1 - m0);
    float inv = 1.f / (1.f + d);
    eidx[2 * n] = b0; eidx[2 * n + 1] = b1;
    probs[2 * n] = inv; probs[2 * n + 1] = d * inv;
    posn[2 * n] = atomicAdd(&counts[b0], 1);
    posn[2 * n + 1] = atomicAdd(&counts[b1], 1);
  }
}

__global__ void k_scan(const int* __restrict__ counts, int* __restrict__ bases) {
  if (threadIdx.x == 0) {
    int s = 0;
    for (int e = 0; e < NE; ++e) { bases[e] = s; s += counts[e]; }
  }
}

__global__ __launch_bounds__(256) void k_build(const int* __restrict__ eidx,
    const int* __restrict__ posn, const int* __restrict__ bases,
    int* __restrict__ rows_of, int* __restrict__ row2tok)
{
  int n = blockIdx.x * 256 + threadIdx.x;
  if (n >= NT) return;
#pragma unroll
  for (int k = 0; k < 2; ++k) {
    int e = eidx[2 * n + k];
    int row = bases[e] + posn[2 * n + k];
    rows_of[2 * n + k] = row;
    row2tok[row] = n;
  }
}

// ---------------- UP: merged shared-up + routed-up (dual B, SwiGLU) --------
// BM=256, BN=128/matrix, BK=64, 512 thr / 8 waves as 4M x 2N (wave 64x64/mat).
// Counted-wait pipeline, waits ALWAYS immediately before a barrier:
//  tile t: {ldA, issue SB(t+1) | ldB0+mmq0 | ldB1+mmq1 | lgk0,BAR |
//           issue SA(t+2)->cur | vm4,BAR}.  SA keeps ~1.5 tiles in flight.
__global__ __launch_bounds__(512, 2) void k_up(
    const unsigned short* __restrict__ xb,
    const unsigned short* __restrict__ w1b, const unsigned short* __restrict__ w3b,
    const unsigned short* __restrict__ sw1b, const unsigned short* __restrict__ sw3b,
    unsigned short* __restrict__ h, unsigned short* __restrict__ hs,
    const int* __restrict__ counts, const int* __restrict__ bases,
    const int* __restrict__ row2tok)
{
  extern __shared__ char sm[];
  constexpr int NSH = (NT / 256) * (SD / 128);            // 176
  constexpr int NWG = NSH + NE * (ID / 128) * (NT / 256); // 880
  constexpr int NSTEP = CD / 64;                          // 32

  int lin = swz8((int)blockIdx.x, NWG);
  int cls, mx, pn, e = 0;
  if (lin < NSH) { cls = 0; mx = lin % 8; pn = lin / 8; }
  else { cls = 1; int r = lin - NSH; mx = r % 8; r /= 8; pn = r % 11; e = r / 11; }

  int M = NT, baserow = 0;
  if (cls) { M = counts[e]; if (mx * 256 >= M) return; baserow = bases[e]; }
  const int m0 = mx * 256, n0 = pn * 128;

  const unsigned short* B1 = cls ? w1b + ((size_t)e * ID + n0) * CD : sw1b + (size_t)n0 * CD;
  const unsigned short* B3 = cls ? w3b + ((size_t)e * ID + n0) * CD : sw3b + (size_t)n0 * CD;

  const int tid = threadIdx.x, l = tid & 63, w = tid >> 6;
  const int wr = w >> 1, wn = w & 1;      // 4M x 2N
  const int slot = ((tid & 7) ^ ((tid >> 3) & 7)) * 16;

  const char* aP[4];
#pragma unroll
  for (int t = 0; t < 4; ++t) {
    int r = t * 64 + (tid >> 3);
    const unsigned short* rb;
    if (cls) {
      int grow = m0 + r; int gr = grow < M ? grow : 0;
      rb = xb + (size_t)row2tok[baserow + gr] * CD;
    } else {
      rb = xb + (size_t)(m0 + r) * CD;
    }
    aP[t] = (const char*)rb + slot;
  }
  const char* bP1[2]; const char* bP3[2];
#pragma unroll
  for (int t = 0; t < 2; ++t) {
    int r = t * 64 + (tid >> 3);
    bP1[t] = (const char*)(B1 + (size_t)r * CD) + slot;
    bP3[t] = (const char*)(B3 + (size_t)r * CD) + slot;
  }

  f32x4 acc1[4][4], acc3[4][4];
#pragma unroll
  for (int m = 0; m < 4; ++m)
#pragma unroll
    for (int n = 0; n < 4; ++n) {
      acc1[m][n] = {0.f, 0.f, 0.f, 0.f};
      acc3[m][n] = {0.f, 0.f, 0.f, 0.f};
    }

  const int lrow = l & 15, lkg = l >> 4, l7 = l & 7;

  auto stageA = [&](char* base, size_t kb) {   // 4 gll
#pragma unroll
    for (int t = 0; t < 4; ++t) gll16(aP[t] + kb, base + t * 8192 + tid * 16);
  };
  auto stageB = [&](char* base, size_t kb) {   // 4 gll
    char* sB1 = base + 32768; char* sB3 = base + 49152;
#pragma unroll
    for (int t = 0; t < 2; ++t) {
      gll16(bP1[t] + kb, sB1 + t * 8192 + tid * 16);
      gll16(bP3[t] + kb, sB3 + t * 8192 + tid * 16);
    }
  };
  auto ldA = [&](bf16x8* fa, const char* cur, int kk) {
    const int ao = ((kk * 4 + lkg) ^ l7) * 16;
#pragma unroll
    for (int m = 0; m < 4; ++m)
      fa[m] = *(const bf16x8*)(cur + (wr * 64 + m * 16 + lrow) * 128 + ao);
  };
  auto ldB = [&](bf16x8* fb1, bf16x8* fb3, const char* cur, int kk) {
    const char* sB1 = cur + 32768; const char* sB3 = cur + 49152;
    const int ao = ((kk * 4 + lkg) ^ l7) * 16;
#pragma unroll
    for (int n = 0; n < 4; ++n) {
      fb1[n] = *(const bf16x8*)(sB1 + (wn * 64 + n * 16 + lrow) * 128 + ao);
      fb3[n] = *(const bf16x8*)(sB3 + (wn * 64 + n * 16 + lrow) * 128 + ao);
    }
  };
  auto mmq = [&](const bf16x8* fa, const bf16x8* fb1, const bf16x8* fb3) {
    __builtin_amdgcn_s_setprio(1);
#pragma unroll
    for (int n = 0; n < 4; ++n)
#pragma unroll
      for (int m = 0; m < 4; ++m) {
        acc1[m][n] = __builtin_amdgcn_mfma_f32_16x16x32_bf16(fa[m], fb1[n], acc1[m][n], 0, 0, 0);
        acc3[m][n] = __builtin_amdgcn_mfma_f32_16x16x32_bf16(fa[m], fb3[n], acc3[m][n], 0, 0, 0);
      }
    __builtin_amdgcn_s_setprio(0);
  };

  // prologue: tile0 (A+B) + tile1 A-half. vm4 drains tile0; SA(1) in flight.
  stageA(sm, 0); stageB(sm, 0);
  stageA(sm + 65536, 128);
  wait_vm4(); bar_sched();

  for (int t = 0; t < NSTEP; ++t) {
    const char* cur = sm + (size_t)(t & 1) * 65536;
    char* nxt = sm + (size_t)((t + 1) & 1) * 65536;
    const bool pf  = (t + 1 < NSTEP);
    const bool pf2 = (t + 2 < NSTEP);
    bf16x8 Fa0[4], Fa1[4], Fb1[4], Fb3[4];
    // p0: A frags of this tile; issue next-tile B-half
    ldA(Fa0, cur, 0);
    ldA(Fa1, cur, 1);
    if (pf) stageB(nxt, (size_t)(t + 1) * 128);
    sched0();
    // p1: B(kk0) + 32 MFMA
    ldB(Fb1, Fb3, cur, 0);
    mmq(Fa0, Fb1, Fb3);
    sched0();
    // p2: B(kk1) + 32 MFMA
    ldB(Fb1, Fb3, cur, 1);
    mmq(Fa1, Fb1, Fb3);
    sched0();
    if (pf) {
      wait_lgk0();
      bar_sched();                               // all waves done reading cur
      if (pf2) stageA((char*)cur, (size_t)(t + 2) * 128);  // overwrite cur A
      if (pf2) wait_vm4(); else wait_vm0();      // drain SA(t+1)+SB(t+1)
      bar_sched();                               // nxt staged & visible
    }
  }

  // epilogue: row = m0 + wr*64 + m*16 + lkg*4 + j; col = n0 + wn*64 + n*16 + lrow
#pragma unroll
  for (int m = 0; m < 4; ++m) {
    int rb_ = m0 + wr * 64 + m * 16 + lkg * 4;
#pragma unroll
    for (int j = 0; j < 4; ++j) {
      int grow = rb_ + j;
      if (cls && grow >= M) continue;
#pragma unroll
      for (int n = 0; n < 4; ++n) {
        int gcol = n0 + wn * 64 + n * 16 + lrow;
        float hh = silu_f(acc1[m][n][j]) * acc3[m][n][j];
        if (cls) h[(size_t)(baserow + grow) * ID + gcol] = f2bf(hh);
        else     hs[(size_t)grow * SD + gcol] = f2bf(hh);
      }
    }
  }
}

// ---------------- DOWN GEMMs (R4 verbatim): counted-vmcnt 128-tile ----------
// MODE 1: routed down : A=h,  B=w2b[e],  epi -> eo (bf16)
// MODE 3: shared down : A=hs, B=sw2b, epi + top2 combine(eo) -> y (f32)
struct GArgs {
  const unsigned short* A;
  const unsigned short* B1;
  void* Out;
  const int* counts; const int* bases;
  const int* rows_of; const float* probs; const unsigned short* eo;
};

template<int MODE>
__global__ __launch_bounds__(256) void k_gemm(GArgs a)
{
  constexpr int KD = (MODE == 1 ? ID : SD);
  constexpr int BN = 128;
  constexpr int NH = BN / 2;
  constexpr int NFT = NH / 16;      // 4
  constexpr int BT = 4;
  constexpr int NMB = NT / 128;
  constexpr int NPN = CD / 128;
  constexpr int NWG = NMB * NPN * ((MODE == 1) ? NE : 1);
  constexpr int NSTEP = KD / 64;    // 22 / 44 (even)

  __shared__ __align__(16) char smem[2][32768];

  int lin = swz_chunk((int)blockIdx.x, NWG);
  const int mx = lin % NMB; lin /= NMB;
  const int pn = lin % NPN;
  const int e  = lin / NPN;

  int M, baserow = 0;
  if constexpr (MODE == 1) {
    int ne = a.counts[e];
    if (mx * 128 >= ne) return;
    M = ne; baserow = a.bases[e];
  } else { M = NT; }
  const int m0 = mx * 128;
  const int n0 = pn * BN;

  const unsigned short* B1;
  if constexpr (MODE == 1) { B1 = a.B1 + ((size_t)e * CD + n0) * ID; }
  else                     { B1 = a.B1 + (size_t)n0 * SD; }

  const int tid = threadIdx.x, l = tid & 63, w = tid >> 6;
  const int wr = w >> 1, wc = w & 1;
  const int slot = ((l & 7) ^ ((l >> 3) & 7)) * 16;

  const char* aP[4];
#pragma unroll
  for (int t = 0; t < 4; ++t) {
    int r = w * 32 + t * 8 + (l >> 3);
    const unsigned short* rb;
    if constexpr (MODE == 1) {
      rb = a.A + (size_t)(baserow + m0 + r) * KD;
    } else {
      rb = a.A + (size_t)(m0 + r) * KD;
    }
    aP[t] = (const char*)rb + slot;
  }
  const char* bP1[BT];
#pragma unroll
  for (int t = 0; t < BT; ++t) {
    int r = w * (8 * BT) + t * 8 + (l >> 3);
    bP1[t] = (const char*)(B1 + (size_t)r * KD) + slot;
  }

  f32x4 acc1[4][NFT];
#pragma unroll
  for (int m = 0; m < 4; ++m)
#pragma unroll
    for (int n = 0; n < NFT; ++n) acc1[m][n] = {0.f, 0.f, 0.f, 0.f};

  const int lrow = l & 15, lkg = l >> 4, l7 = l & 7;
  const int ao0 = (lkg ^ l7) * 16;
  const int ao1 = ((4 + lkg) ^ l7) * 16;

  auto stageF = [&](char* base, size_t kb) {
    char* sA = base; char* sB1 = base + 16384;
#pragma unroll
    for (int t = 0; t < 4; ++t) gll16(aP[t] + kb, sA + (w * 4 + t) * 1024);
#pragma unroll
    for (int t = 0; t < BT; ++t) gll16(bP1[t] + kb, sB1 + (w * BT + t) * 1024);
  };
  auto computeF = [&](const char* base) {
    const char* sA = base; const char* sB1 = base + 16384;
#pragma unroll
    for (int kk = 0; kk < 2; ++kk) {
      const int ao = kk ? ao1 : ao0;
      bf16x8 af[4];
#pragma unroll
      for (int m = 0; m < 4; ++m)
        af[m] = *(const bf16x8*)(sA + (wr * 64 + m * 16 + lrow) * 128 + ao);
#pragma unroll
      for (int n = 0; n < NFT; ++n) {
        bf16x8 b1 = *(const bf16x8*)(sB1 + (wc * NH + n * 16 + lrow) * 128 + ao);
#pragma unroll
        for (int m = 0; m < 4; ++m)
          acc1[m][n] = __builtin_amdgcn_mfma_f32_16x16x32_bf16(af[m], b1, acc1[m][n], 0, 0, 0);
      }
    }
  };

  stageF(smem[0], 0);
  int t = 0;
  for (; t < NSTEP - 2; t += 2) {
    stageF(smem[1], (size_t)(t + 1) * 128);
    wait_vm8(); bar_sched();
    computeF(smem[0]);
    wait_lgk0(); bar_sched();
    stageF(smem[0], (size_t)(t + 2) * 128);
    wait_vm8(); bar_sched();
    computeF(smem[1]);
    wait_lgk0(); bar_sched();
  }
  stageF(smem[1], (size_t)(NSTEP - 1) * 128);
  wait_vm8(); bar_sched();
  computeF(smem[0]);
  wait_vm0(); bar_sched();
  computeF(smem[1]);

#pragma unroll
  for (int m = 0; m < 4; ++m) {
    int rbase = m0 + wr * 64 + m * 16 + lkg * 4;
#pragma unroll
    for (int j = 0; j < 4; ++j) {
      int grow = rbase + j;
      if constexpr (MODE == 1) { if (grow >= M) continue; }
      int r0 = 0, r1 = 0; float p0 = 0.f, p1 = 0.f;
      if constexpr (MODE == 3) {
        r0 = a.rows_of[2 * grow]; r1 = a.rows_of[2 * grow + 1];
        p0 = a.probs[2 * grow];   p1 = a.probs[2 * grow + 1];
      }
#pragma unroll
      for (int n = 0; n < NFT; ++n) {
        int gcol = n0 + wc * NH + n * 16 + lrow;
        float v1 = acc1[m][n][j];
        if constexpr (MODE == 1) {
          ((unsigned short*)a.Out)[(size_t)(baserow + grow) * CD + gcol] = f2bf(v1);
        } else {
          float vv = v1 + p0 * bf2f(a.eo[(size_t)r0 * CD + gcol]) + p1 * bf2f(a.eo[(size_t)r1 * CD + gcol]);
          ((float*)a.Out)[(size_t)grow * CD + gcol] = vv;
        }
      }
    }
  }
}

// ---------------- launch ---------------------------------------------------
extern "C" void kernel_launch(void* const* d_in, const int* in_sizes, int n_in,
                              void* d_out, int out_size, void* d_ws, size_t ws_size,
                              hipStream_t stream)
{
  const float* x   = (const float*)d_in[0];
  const float* gw  = (const float*)d_in[1];
  const float* w1  = (const float*)d_in[2];
  const float* w3  = (const float*)d_in[3];
  const float* w2  = (const float*)d_in[4];
  const float* sw1 = (const float*)d_in[5];
  const float* sw3 = (const float*)d_in[6];
  const float* sw2 = (const float*)d_in[7];
  float* y = (float*)d_out;

  char* p = (char*)d_ws;
  auto alloc = [&](size_t b) { char* r = p; p += (b + 255) & ~(size_t)255; return r; };
  int*   counts  = (int*)alloc(NE * 4);
  int*   bases   = (int*)alloc(NE * 4);
  int*   eidx    = (int*)alloc((size_t)NT * 2 * 4);
  int*   posn    = (int*)alloc((size_t)NT * 2 * 4);
  float* probs   = (float*)alloc((size_t)NT * 2 * 4);
  int*   rows_of = (int*)alloc((size_t)NT * 2 * 4);
  int*   row2tok = (int*)alloc((size_t)ROWS * 4);
  unsigned short* xb   = (unsigned short*)alloc((size_t)NT * CD * 2);
  unsigned short* w1b  = (unsigned short*)alloc((size_t)NE * ID * CD * 2);
  unsigned short* w3b  = (unsigned short*)alloc((size_t)NE * ID * CD * 2);
  unsigned short* w2b  = (unsigned short*)alloc((size_t)NE * CD * ID * 2);
  unsigned short* sw1b = (unsigned short*)alloc((size_t)SD * CD * 2);
  unsigned short* sw3b = (unsigned short*)alloc((size_t)SD * CD * 2);
  unsigned short* sw2b = (unsigned short*)alloc((size_t)CD * SD * 2);
  unsigned short* h    = (unsigned short*)alloc((size_t)ROWS_PAD * ID * 2);
  unsigned short* eo   = (unsigned short*)alloc((size_t)ROWS_PAD * CD * 2);
  unsigned short* hs   = (unsigned short*)alloc((size_t)NT * SD * 2);

  hipFuncSetAttribute((const void*)k_up, hipFuncAttributeMaxDynamicSharedMemorySize, 131072);

  hipMemsetAsync(counts, 0, NE * 4, stream);

  {
    Cvt7 c{};
    const float* ss[7] = {x, w1, w3, w2, sw1, sw3, sw2};
    unsigned short* dd[7] = {xb, w1b, w3b, w2b, sw1b, sw3b, sw2b};
    size_t nn[7] = {(size_t)NT * CD, (size_t)NE * ID * CD, (size_t)NE * ID * CD,
                    (size_t)NE * CD * ID, (size_t)SD * CD, (size_t)SD * CD,
                    (size_t)CD * SD};
    long long acc = 0;
    for (int k = 0; k < 7; ++k) {
      c.s[k] = ss[k]; c.d[k] = dd[k]; c.beg[k] = acc; acc += (long long)(nn[k] / 8);
    }
    c.beg[7] = acc;
    k_cvt7<<<2048, 256, 0, stream>>>(c);
  }

  k_router<<<NT, 64, 0, stream>>>(x, gw, counts, eidx, posn, probs);
  k_scan<<<1, 64, 0, stream>>>(counts, bases);
  k_build<<<NT / 256, 256, 0, stream>>>(eidx, posn, bases, rows_of, row2tok);

  {
    constexpr int NWG = (NT / 256) * (SD / 128) + NE * (ID / 128) * (NT / 256); // 880
    k_up<<<NWG, 512, 131072, stream>>>(xb, w1b, w3b, sw1b, sw3b, h, hs,
                                       counts, bases, row2tok);
  }
  {
    GArgs g{}; g.A = h; g.B1 = w2b; g.Out = eo;
    g.counts = counts; g.bases = bases;
    k_gemm<1><<<(NT / 128) * (CD / 128) * NE, 256, 0, stream>>>(g);
  }
  {
    GArgs g{}; g.A = hs; g.B1 = sw2b; g.Out = y;
    g.rows_of = rows_of; g.probs = probs; g.eo = eo;
    k_gemm<3><<<(NT / 128) * (CD / 128), 256, 0, stream>>>(g);
  }
}

// Round 12
// 409.281 us; speedup vs baseline: 1.0230x; 1.0230x over previous
//
#include <hip/hip_runtime.h>

#define DEVI __device__ __forceinline__

typedef __attribute__((ext_vector_type(4))) float f32x4;
typedef __attribute__((ext_vector_type(8))) short bf16x8;

static constexpr int NT = 2048;   // tokens
static constexpr int CD = 2048;   // model dim
static constexpr int NE = 8;      // experts
static constexpr int ID = 1408;   // expert ffn dim
static constexpr int SD = 2816;   // shared ffn dim
static constexpr int ROWS = 2 * NT;
static constexpr int ROWS_PAD = ROWS + 256;

DEVI unsigned short f2bf(float f) {
  unsigned u = __builtin_bit_cast(unsigned, f);
  u += 0x7fff + ((u >> 16) & 1);           // RNE
  return (unsigned short)(u >> 16);
}
DEVI float bf2f(unsigned short s) { return __builtin_bit_cast(float, (unsigned)s << 16); }
DEVI float silu_f(float z) { return z / (1.f + __expf(-z)); }

DEVI void gll16(const void* g, void* l) {
  __builtin_amdgcn_global_load_lds((__attribute__((address_space(1))) void*)(void*)g,
                                   (__attribute__((address_space(3))) void*)l, 16, 0, 0);
}

DEVI void bar_sched() {
  __builtin_amdgcn_s_barrier();
  __builtin_amdgcn_sched_barrier(0);
}
DEVI void sched0() { __builtin_amdgcn_sched_barrier(0); }
DEVI void wait_vm8() { asm volatile("s_waitcnt vmcnt(8)" ::: "memory"); }
DEVI void wait_vm0() { asm volatile("s_waitcnt vmcnt(0)" ::: "memory"); }
DEVI void wait_lgk0() { asm volatile("s_waitcnt lgkmcnt(0)" ::: "memory"); }

// bijective XCD-chunk swizzle, CH=8 (512-thr kernels)
DEVI int swz8(int bid, int nwg) {
  constexpr int CH = 8, G = 64;
  int nfull = nwg - (nwg % G);
  if (bid >= nfull) return bid;
  int c = bid / G, r = bid % G;
  return c * G + (r % 8) * CH + (r / 8);
}
// bijective XCD-chunk swizzle, CH=16 (256-thr GEMMs)
DEVI int swz_chunk(int bid, int nwg) {
  constexpr int CH = 16, G = 8 * CH;
  int nfull = nwg - (nwg % G);
  if (bid >= nfull) return bid;
  int c = bid / G, r = bid % G;
  return c * G + (r % 8) * CH + (r / 8);
}

// ---------------- fused fp32 -> bf16 convert (7 tensors, one dispatch) -----
struct Cvt7 {
  const float* s[7];
  unsigned short* d[7];
  long long beg[8];   // prefix sums, units of 8-element groups
};
__global__ __launch_bounds__(256) void k_cvt7(Cvt7 c)
{
  const long long total = c.beg[7];
  const long long stride = (long long)gridDim.x * 256;
  for (long long i = (long long)blockIdx.x * 256 + threadIdx.x; i < total; i += stride) {
    int sg = 0;
#pragma unroll
    for (int k = 1; k < 7; ++k) if (i >= c.beg[k]) sg = k;
    long long j = i - c.beg[sg];
    float4 a = ((const float4*)c.s[sg])[2 * j];
    float4 b = ((const float4*)c.s[sg])[2 * j + 1];
    ushort4 p0 = make_ushort4(f2bf(a.x), f2bf(a.y), f2bf(a.z), f2bf(a.w));
    ushort4 p1 = make_ushort4(f2bf(b.x), f2bf(b.y), f2bf(b.z), f2bf(b.w));
    ((ushort4*)c.d[sg])[2 * j]     = p0;
    ((ushort4*)c.d[sg])[2 * j + 1] = p1;
  }
}

// ---------------- router ---------------------------------------------------
__global__ __launch_bounds__(64) void k_router(const float* __restrict__ x,
    const float* __restrict__ gw, int* __restrict__ counts,
    int* __restrict__ eidx, int* __restrict__ posn, float* __restrict__ probs)
{
  const int n = blockIdx.x;
  const int lane = threadIdx.x;
  const float4* xr = (const float4*)(x + (size_t)n * CD);
  float acc[NE];
#pragma unroll
  for (int e = 0; e < NE; ++e) acc[e] = 0.f;
  for (int i = lane; i < CD / 4; i += 64) {
    float4 xv = xr[i];
#pragma unroll
    for (int e = 0; e < NE; ++e) {
      float4 gv = ((const float4*)(gw + (size_t)e * CD))[i];
      acc[e] += xv.x * gv.x + xv.y * gv.y + xv.z * gv.z + xv.w * gv.w;
    }
  }
#pragma unroll
  for (int e = 0; e < NE; ++e) {
    float v = acc[e];
#pragma unroll
    for (int off = 32; off > 0; off >>= 1) v += __shfl_down(v, off);
    acc[e] = v;
  }
  if (lane == 0) {
    int b0 = 0; float m0 = acc[0];
#pragma unroll
    for (int e = 1; e < NE; ++e) if (acc[e] > m0) { m0 = acc[e]; b0 = e; }
    int b1 = -1; float m1 = 0.f;
#pragma unroll
    for (int e = 0; e < NE; ++e) {
      if (e == b0) continue;
      if (b1 < 0 || acc[e] > m1) { m1 = acc[e]; b1 = e; }
    }
    float d = __expf(m1 - m0);
    float inv = 1.f / (1.f + d);
    eidx[2 * n] = b0; eidx[2 * n + 1] = b1;
    probs[2 * n] = inv; probs[2 * n + 1] = d * inv;
    posn[2 * n] = atomicAdd(&counts[b0], 1);
    posn[2 * n + 1] = atomicAdd(&counts[b1], 1);
  }
}

__global__ void k_scan(const int* __restrict__ counts, int* __restrict__ bases) {
  if (threadIdx.x == 0) {
    int s = 0;
    for (int e = 0; e < NE; ++e) { bases[e] = s; s += counts[e]; }
  }
}

__global__ __launch_bounds__(256) void k_build(const int* __restrict__ eidx,
    const int* __restrict__ posn, const int* __restrict__ bases,
    int* __restrict__ rows_of, int* __restrict__ row2tok)
{
  int n = blockIdx.x * 256 + threadIdx.x;
  if (n >= NT) return;
#pragma unroll
  for (int k = 0; k < 2; ++k) {
    int e = eidx[2 * n + k];
    int row = bases[e] + posn[2 * n + k];
    rows_of[2 * n + k] = row;
    row2tok[row] = n;
  }
}

// ---------------- UP: merged shared-up + routed-up (R6 verbatim) -----------
// BM=256, BN=128 per matrix, BK=64, 512 thr / 8 waves (2M x 4N of 128x32).
// 4-phase interleaved K-tile, ONE barrier + ONE vm-wait per tile. XOR swizzle.
__global__ __launch_bounds__(512, 2) void k_up(
    const unsigned short* __restrict__ xb,
    const unsigned short* __restrict__ w1b, const unsigned short* __restrict__ w3b,
    const unsigned short* __restrict__ sw1b, const unsigned short* __restrict__ sw3b,
    unsigned short* __restrict__ h, unsigned short* __restrict__ hs,
    const int* __restrict__ counts, const int* __restrict__ bases,
    const int* __restrict__ row2tok)
{
  extern __shared__ char sm[];
  constexpr int NSH = (NT / 256) * (SD / 128);            // 176
  constexpr int NWG = NSH + NE * (ID / 128) * (NT / 256); // 880
  constexpr int NSTEP = CD / 64;                          // 32

  int lin = swz8((int)blockIdx.x, NWG);
  int cls, mx, pn, e = 0;
  if (lin < NSH) { cls = 0; mx = lin % 8; pn = lin / 8; }
  else { cls = 1; int r = lin - NSH; mx = r % 8; r /= 8; pn = r % 11; e = r / 11; }

  int M = NT, baserow = 0;
  if (cls) { M = counts[e]; if (mx * 256 >= M) return; baserow = bases[e]; }
  const int m0 = mx * 256, n0 = pn * 128;

  const unsigned short* B1 = cls ? w1b + ((size_t)e * ID + n0) * CD : sw1b + (size_t)n0 * CD;
  const unsigned short* B3 = cls ? w3b + ((size_t)e * ID + n0) * CD : sw3b + (size_t)n0 * CD;

  const int tid = threadIdx.x, l = tid & 63, w = tid >> 6;
  const int wr = w >> 2, wn = w & 3;
  const int slot = ((tid & 7) ^ ((tid >> 3) & 7)) * 16;

  const char* aP[4];
#pragma unroll
  for (int t = 0; t < 4; ++t) {
    int r = t * 64 + (tid >> 3);
    const unsigned short* rb;
    if (cls) {
      int grow = m0 + r; int gr = grow < M ? grow : 0;
      rb = xb + (size_t)row2tok[baserow + gr] * CD;
    } else {
      rb = xb + (size_t)(m0 + r) * CD;
    }
    aP[t] = (const char*)rb + slot;
  }
  const char* bP1[2]; const char* bP3[2];
#pragma unroll
  for (int t = 0; t < 2; ++t) {
    int r = t * 64 + (tid >> 3);
    bP1[t] = (const char*)(B1 + (size_t)r * CD) + slot;
    bP3[t] = (const char*)(B3 + (size_t)r * CD) + slot;
  }

  f32x4 acc1[8][2], acc3[8][2];
#pragma unroll
  for (int m = 0; m < 8; ++m)
#pragma unroll
    for (int n = 0; n < 2; ++n) {
      acc1[m][n] = {0.f, 0.f, 0.f, 0.f};
      acc3[m][n] = {0.f, 0.f, 0.f, 0.f};
    }

  const int lrow = l & 15, lkg = l >> 4, l7 = l & 7;

  auto stage_first = [&](char* base, size_t kb) {   // A half: 4 gll
#pragma unroll
    for (int t = 0; t < 4; ++t) gll16(aP[t] + kb, base + t * 8192 + tid * 16);
  };
  auto stage_second = [&](char* base, size_t kb) {  // B half: 4 gll
    char* sB1 = base + 32768; char* sB3 = base + 49152;
#pragma unroll
    for (int t = 0; t < 2; ++t) {
      gll16(bP1[t] + kb, sB1 + t * 8192 + tid * 16);
      gll16(bP3[t] + kb, sB3 + t * 8192 + tid * 16);
    }
  };
  auto ldq = [&](bf16x8* fa, bf16x8* fb1, bf16x8* fb3, const char* cur, int mh, int kk) {
    const char* sA = cur; const char* sB1 = cur + 32768; const char* sB3 = cur + 49152;
    const int ao = ((kk * 4 + lkg) ^ l7) * 16;
#pragma unroll
    for (int m = 0; m < 4; ++m)
      fa[m] = *(const bf16x8*)(sA + (wr * 128 + mh * 64 + m * 16 + lrow) * 128 + ao);
#pragma unroll
    for (int n = 0; n < 2; ++n) {
      fb1[n] = *(const bf16x8*)(sB1 + (wn * 32 + n * 16 + lrow) * 128 + ao);
      fb3[n] = *(const bf16x8*)(sB3 + (wn * 32 + n * 16 + lrow) * 128 + ao);
    }
  };
  auto mmq = [&](const bf16x8* fa, const bf16x8* fb1, const bf16x8* fb3, int mh) {
    __builtin_amdgcn_s_setprio(1);
#pragma unroll
    for (int n = 0; n < 2; ++n)
#pragma unroll
      for (int m = 0; m < 4; ++m) {
        acc1[mh * 4 + m][n] = __builtin_amdgcn_mfma_f32_16x16x32_bf16(fa[m], fb1[n], acc1[mh * 4 + m][n], 0, 0, 0);
        acc3[mh * 4 + m][n] = __builtin_amdgcn_mfma_f32_16x16x32_bf16(fa[m], fb3[n], acc3[mh * 4 + m][n], 0, 0, 0);
      }
    __builtin_amdgcn_s_setprio(0);
  };

  stage_first(sm, 0);
  stage_second(sm, 0);
  wait_vm0(); bar_sched();

  bf16x8 Xa[4], Xb1[2], Xb3[2], Ya[4], Yb1[2], Yb3[2];

  for (int t = 0; t < NSTEP; ++t) {
    char* cur = sm + (size_t)(t & 1) * 65536;
    char* nxt = sm + (size_t)((t + 1) & 1) * 65536;
    size_t kb = (size_t)(t + 1) * 128;
    ldq(Xa, Xb1, Xb3, cur, 0, 0);
    sched0();
    if (t + 1 < NSTEP) stage_first(nxt, kb);          // phase 0
    ldq(Ya, Yb1, Yb3, cur, 1, 0);
    mmq(Xa, Xb1, Xb3, 0);
    sched0();
    if (t + 1 < NSTEP) stage_second(nxt, kb);         // phase 1
    ldq(Xa, Xb1, Xb3, cur, 0, 1);
    mmq(Ya, Yb1, Yb3, 1);
    sched0();
    ldq(Ya, Yb1, Yb3, cur, 1, 1);                     // phase 2
    mmq(Xa, Xb1, Xb3, 0);
    sched0();
    mmq(Ya, Yb1, Yb3, 1);                             // phase 3
    sched0();
    wait_vm0(); wait_lgk0();
    bar_sched();
  }

#pragma unroll
  for (int m = 0; m < 8; ++m) {
    int rb_ = m0 + wr * 128 + m * 16 + lkg * 4;
#pragma unroll
    for (int j = 0; j < 4; ++j) {
      int grow = rb_ + j;
      if (cls && grow >= M) continue;
#pragma unroll
      for (int n = 0; n < 2; ++n) {
        int gcol = n0 + wn * 32 + n * 16 + lrow;
        float hh = silu_f(acc1[m][n][j]) * acc3[m][n][j];
        if (cls) h[(size_t)(baserow + grow) * ID + gcol] = f2bf(hh);
        else     hs[(size_t)grow * SD + gcol] = f2bf(hh);
      }
    }
  }
}

// ---------------- DOWN GEMMs (R4 verbatim): counted-vmcnt 128-tile ----------
// MODE 1: routed down : A=h,  B=w2b[e],  epi -> eo (bf16)
// MODE 3: shared down : A=hs, B=sw2b, epi + top2 combine(eo) -> y (f32)
struct GArgs {
  const unsigned short* A;
  const unsigned short* B1;
  void* Out;
  const int* counts; const int* bases;
  const int* rows_of; const float* probs; const unsigned short* eo;
};

template<int MODE>
__global__ __launch_bounds__(256) void k_gemm(GArgs a)
{
  constexpr int KD = (MODE == 1 ? ID : SD);
  constexpr int BN = 128;
  constexpr int NH = BN / 2;
  constexpr int NFT = NH / 16;      // 4
  constexpr int BT = 4;
  constexpr int NMB = NT / 128;
  constexpr int NPN = CD / 128;
  constexpr int NWG = NMB * NPN * ((MODE == 1) ? NE : 1);
  constexpr int NSTEP = KD / 64;    // 22 / 44 (even)

  __shared__ __align__(16) char smem[2][32768];

  int lin = swz_chunk((int)blockIdx.x, NWG);
  const int mx = lin % NMB; lin /= NMB;
  const int pn = lin % NPN;
  const int e  = lin / NPN;

  int M, baserow = 0;
  if constexpr (MODE == 1) {
    int ne = a.counts[e];
    if (mx * 128 >= ne) return;
    M = ne; baserow = a.bases[e];
  } else { M = NT; }
  const int m0 = mx * 128;
  const int n0 = pn * BN;

  const unsigned short* B1;
  if constexpr (MODE == 1) { B1 = a.B1 + ((size_t)e * CD + n0) * ID; }
  else                     { B1 = a.B1 + (size_t)n0 * SD; }

  const int tid = threadIdx.x, l = tid & 63, w = tid >> 6;
  const int wr = w >> 1, wc = w & 1;
  const int slot = ((l & 7) ^ ((l >> 3) & 7)) * 16;

  const char* aP[4];
#pragma unroll
  for (int t = 0; t < 4; ++t) {
    int r = w * 32 + t * 8 + (l >> 3);
    const unsigned short* rb;
    if constexpr (MODE == 1) {
      rb = a.A + (size_t)(baserow + m0 + r) * KD;
    } else {
      rb = a.A + (size_t)(m0 + r) * KD;
    }
    aP[t] = (const char*)rb + slot;
  }
  const char* bP1[BT];
#pragma unroll
  for (int t = 0; t < BT; ++t) {
    int r = w * (8 * BT) + t * 8 + (l >> 3);
    bP1[t] = (const char*)(B1 + (size_t)r * KD) + slot;
  }

  f32x4 acc1[4][NFT];
#pragma unroll
  for (int m = 0; m < 4; ++m)
#pragma unroll
    for (int n = 0; n < NFT; ++n) acc1[m][n] = {0.f, 0.f, 0.f, 0.f};

  const int lrow = l & 15, lkg = l >> 4, l7 = l & 7;
  const int ao0 = (lkg ^ l7) * 16;
  const int ao1 = ((4 + lkg) ^ l7) * 16;

  auto stageF = [&](char* base, size_t kb) {
    char* sA = base; char* sB1 = base + 16384;
#pragma unroll
    for (int t = 0; t < 4; ++t) gll16(aP[t] + kb, sA + (w * 4 + t) * 1024);
#pragma unroll
    for (int t = 0; t < BT; ++t) gll16(bP1[t] + kb, sB1 + (w * BT + t) * 1024);
  };
  auto computeF = [&](const char* base) {
    const char* sA = base; const char* sB1 = base + 16384;
#pragma unroll
    for (int kk = 0; kk < 2; ++kk) {
      const int ao = kk ? ao1 : ao0;
      bf16x8 af[4];
#pragma unroll
      for (int m = 0; m < 4; ++m)
        af[m] = *(const bf16x8*)(sA + (wr * 64 + m * 16 + lrow) * 128 + ao);
#pragma unroll
      for (int n = 0; n < NFT; ++n) {
        bf16x8 b1 = *(const bf16x8*)(sB1 + (wc * NH + n * 16 + lrow) * 128 + ao);
#pragma unroll
        for (int m = 0; m < 4; ++m)
          acc1[m][n] = __builtin_amdgcn_mfma_f32_16x16x32_bf16(af[m], b1, acc1[m][n], 0, 0, 0);
      }
    }
  };

  stageF(smem[0], 0);
  int t = 0;
  for (; t < NSTEP - 2; t += 2) {
    stageF(smem[1], (size_t)(t + 1) * 128);
    wait_vm8(); bar_sched();
    computeF(smem[0]);
    wait_lgk0(); bar_sched();
    stageF(smem[0], (size_t)(t + 2) * 128);
    wait_vm8(); bar_sched();
    computeF(smem[1]);
    wait_lgk0(); bar_sched();
  }
  stageF(smem[1], (size_t)(NSTEP - 1) * 128);
  wait_vm8(); bar_sched();
  computeF(smem[0]);
  wait_vm0(); bar_sched();
  computeF(smem[1]);

#pragma unroll
  for (int m = 0; m < 4; ++m) {
    int rbase = m0 + wr * 64 + m * 16 + lkg * 4;
#pragma unroll
    for (int j = 0; j < 4; ++j) {
      int grow = rbase + j;
      if constexpr (MODE == 1) { if (grow >= M) continue; }
      int r0 = 0, r1 = 0; float p0 = 0.f, p1 = 0.f;
      if constexpr (MODE == 3) {
        r0 = a.rows_of[2 * grow]; r1 = a.rows_of[2 * grow + 1];
        p0 = a.probs[2 * grow];   p1 = a.probs[2 * grow + 1];
      }
#pragma unroll
      for (int n = 0; n < NFT; ++n) {
        int gcol = n0 + wc * NH + n * 16 + lrow;
        float v1 = acc1[m][n][j];
        if constexpr (MODE == 1) {
          ((unsigned short*)a.Out)[(size_t)(baserow + grow) * CD + gcol] = f2bf(v1);
        } else {
          float vv = v1 + p0 * bf2f(a.eo[(size_t)r0 * CD + gcol]) + p1 * bf2f(a.eo[(size_t)r1 * CD + gcol]);
          ((float*)a.Out)[(size_t)grow * CD + gcol] = vv;
        }
      }
    }
  }
}

// ---------------- launch ---------------------------------------------------
extern "C" void kernel_launch(void* const* d_in, const int* in_sizes, int n_in,
                              void* d_out, int out_size, void* d_ws, size_t ws_size,
                              hipStream_t stream)
{
  const float* x   = (const float*)d_in[0];
  const float* gw  = (const float*)d_in[1];
  const float* w1  = (const float*)d_in[2];
  const float* w3  = (const float*)d_in[3];
  const float* w2  = (const float*)d_in[4];
  const float* sw1 = (const float*)d_in[5];
  const float* sw3 = (const float*)d_in[6];
  const float* sw2 = (const float*)d_in[7];
  float* y = (float*)d_out;

  char* p = (char*)d_ws;
  auto alloc = [&](size_t b) { char* r = p; p += (b + 255) & ~(size_t)255; return r; };
  int*   counts  = (int*)alloc(NE * 4);
  int*   bases   = (int*)alloc(NE * 4);
  int*   eidx    = (int*)alloc((size_t)NT * 2 * 4);
  int*   posn    = (int*)alloc((size_t)NT * 2 * 4);
  float* probs   = (float*)alloc((size_t)NT * 2 * 4);
  int*   rows_of = (int*)alloc((size_t)NT * 2 * 4);
  int*   row2tok = (int*)alloc((size_t)ROWS * 4);
  unsigned short* xb   = (unsigned short*)alloc((size_t)NT * CD * 2);
  unsigned short* w1b  = (unsigned short*)alloc((size_t)NE * ID * CD * 2);
  unsigned short* w3b  = (unsigned short*)alloc((size_t)NE * ID * CD * 2);
  unsigned short* w2b  = (unsigned short*)alloc((size_t)NE * CD * ID * 2);
  unsigned short* sw1b = (unsigned short*)alloc((size_t)SD * CD * 2);
  unsigned short* sw3b = (unsigned short*)alloc((size_t)SD * CD * 2);
  unsigned short* sw2b = (unsigned short*)alloc((size_t)CD * SD * 2);
  unsigned short* h    = (unsigned short*)alloc((size_t)ROWS_PAD * ID * 2);
  unsigned short* eo   = (unsigned short*)alloc((size_t)ROWS_PAD * CD * 2);
  unsigned short* hs   = (unsigned short*)alloc((size_t)NT * SD * 2);

  hipFuncSetAttribute((const void*)k_up, hipFuncAttributeMaxDynamicSharedMemorySize, 131072);

  hipMemsetAsync(counts, 0, NE * 4, stream);

  {
    Cvt7 c{};
    const float* ss[7] = {x, w1, w3, w2, sw1, sw3, sw2};
    unsigned short* dd[7] = {xb, w1b, w3b, w2b, sw1b, sw3b, sw2b};
    size_t nn[7] = {(size_t)NT * CD, (size_t)NE * ID * CD, (size_t)NE * ID * CD,
                    (size_t)NE * CD * ID, (size_t)SD * CD, (size_t)SD * CD,
                    (size_t)CD * SD};
    long long acc = 0;
    for (int k = 0; k < 7; ++k) {
      c.s[k] = ss[k]; c.d[k] = dd[k]; c.beg[k] = acc; acc += (long long)(nn[k] / 8);
    }
    c.beg[7] = acc;
    k_cvt7<<<2048, 256, 0, stream>>>(c);
  }

  k_router<<<NT, 64, 0, stream>>>(x, gw, counts, eidx, posn, probs);
  k_scan<<<1, 64, 0, stream>>>(counts, bases);
  k_build<<<NT / 256, 256, 0, stream>>>(eidx, posn, bases, rows_of, row2tok);

  {
    constexpr int NWG = (NT / 256) * (SD / 128) + NE * (ID / 128) * (NT / 256); // 880
    k_up<<<NWG, 512, 131072, stream>>>(xb, w1b, w3b, sw1b, sw3b, h, hs,
                                       counts, bases, row2tok);
  }
  {
    GArgs g{}; g.A = h; g.B1 = w2b; g.Out = eo;
    g.counts = counts; g.bases = bases;
    k_gemm<1><<<(NT / 128) * (CD / 128) * NE, 256, 0, stream>>>(g);
  }
  {
    GArgs g{}; g.A = hs; g.B1 = sw2b; g.Out = y;
    g.rows_of = rows_of; g.probs = probs; g.eo = eo;
    k_gemm<3><<<(NT / 128) * (CD / 128), 256, 0, stream>>>(g);
  }
}